// Round 7
// baseline (177.463 us; speedup 1.0000x reference)
//
#include <hip/hip_runtime.h>

#define N_NODES 40000
#define E_EDGES 640000
#define E_TOT   (E_EDGES + N_NODES)
#define SCAN_BLOCKS ((N_NODES + 255) / 256)   // 157

typedef unsigned int uint;
typedef unsigned short ushort;

// bf16 helpers (RNE pack, cheap unpack)
__device__ __forceinline__ ushort f2bf(float f) {
    uint u = __float_as_uint(f);
    u += 0x7FFFu + ((u >> 16) & 1u);
    return (ushort)(u >> 16);
}
__device__ __forceinline__ uint pk_bf(float lo, float hi) {
    return (uint)f2bf(lo) | ((uint)f2bf(hi) << 16);
}
__device__ __forceinline__ float bf_lo(uint w) { return __uint_as_float(w << 16); }
__device__ __forceinline__ float bf_hi(uint w) { return __uint_as_float(w & 0xFFFF0000u); }

// ===========================================================================
// Zero histogram counters (tiny; must precede gemm1's fused histogram tail).
// ===========================================================================
__global__ __launch_bounds__(256) void zero_cnt_kernel(int4* __restrict__ cnt4)
{
    const int i = blockIdx.x * 256 + threadIdx.x;
    if (i < 40064 / 4) cnt4[i] = make_int4(0, 0, 0, 0);
}

// ===========================================================================
// GEMM1: h1 = x @ W1  [40000x128 @ 128x128]; h1 stored bf16; fused per-node
// attention coeffs; fused grid-stride histogram tail (overlaps GEMM work).
// ===========================================================================
__global__ __launch_bounds__(256) void gemm1_kernel(
    const float* __restrict__ x, const float* __restrict__ W,
    const float* __restrict__ a_src, const float* __restrict__ a_dst,
    ushort* __restrict__ h1b, float* __restrict__ asrc, float* __restrict__ adst,
    const int* __restrict__ eidx, int* __restrict__ cnt)
{
    __shared__ float Ws[128 * 128];   // 64 KB
    {
        const float4* Wg = (const float4*)W;
        float4* Wl = (float4*)Ws;
        for (int i = threadIdx.x; i < 128 * 128 / 4; i += 256) Wl[i] = Wg[i];
    }
    __syncthreads();
    const int row0 = blockIdx.x * 64;
    const int tx = threadIdx.x & 15;   // 16 col-groups of 8 cols
    const int ty = threadIdx.x >> 4;   // 16 row-groups of 4 rows

    float acc[4][8];
#pragma unroll
    for (int r = 0; r < 4; ++r)
#pragma unroll
        for (int c = 0; c < 8; ++c) acc[r][c] = 0.f;

    for (int k0 = 0; k0 < 128; k0 += 4) {
        float xv[4][4];
#pragma unroll
        for (int r = 0; r < 4; ++r) {
            float4 t = *(const float4*)&x[(size_t)(row0 + ty * 4 + r) * 128 + k0];
            xv[r][0] = t.x; xv[r][1] = t.y; xv[r][2] = t.z; xv[r][3] = t.w;
        }
#pragma unroll
        for (int kk = 0; kk < 4; ++kk) {
            float wreg[8];
            float4 w0 = *(const float4*)&Ws[(k0 + kk) * 128 + tx * 8];
            float4 w1 = *(const float4*)&Ws[(k0 + kk) * 128 + tx * 8 + 4];
            wreg[0] = w0.x; wreg[1] = w0.y; wreg[2] = w0.z; wreg[3] = w0.w;
            wreg[4] = w1.x; wreg[5] = w1.y; wreg[6] = w1.z; wreg[7] = w1.w;
#pragma unroll
            for (int r = 0; r < 4; ++r)
#pragma unroll
                for (int c = 0; c < 8; ++c)
                    acc[r][c] = fmaf(xv[r][kk], wreg[c], acc[r][c]);
        }
    }

    const int head  = tx >> 2;
    const int cbase = (tx & 3) * 8;
    float as[8], ad[8];
#pragma unroll
    for (int c = 0; c < 8; ++c) {
        as[c] = a_src[head * 32 + cbase + c];
        ad[c] = a_dst[head * 32 + cbase + c];
    }
#pragma unroll
    for (int r = 0; r < 4; ++r) {
        const int n = row0 + ty * 4 + r;
        uint4 o;
        o.x = pk_bf(acc[r][0], acc[r][1]);
        o.y = pk_bf(acc[r][2], acc[r][3]);
        o.z = pk_bf(acc[r][4], acc[r][5]);
        o.w = pk_bf(acc[r][6], acc[r][7]);
        *(uint4*)&h1b[(size_t)n * 128 + tx * 8] = o;
        float ps = 0.f, pd = 0.f;
#pragma unroll
        for (int c = 0; c < 8; ++c) {
            ps = fmaf(acc[r][c], as[c], ps);
            pd = fmaf(acc[r][c], ad[c], pd);
        }
        ps += __shfl_xor(ps, 1); ps += __shfl_xor(ps, 2);
        pd += __shfl_xor(pd, 1); pd += __shfl_xor(pd, 2);
        if ((threadIdx.x & 3) == 0) {
            asrc[n * 4 + head] = ps;
            adst[n * 4 + head] = pd;
        }
    }

    // ---- fused histogram tail (grid-stride over all edges + self-loops) ----
    for (int e = blockIdx.x * 256 + threadIdx.x; e < E_TOT; e += 625 * 256) {
        const int d = (e < E_EDGES) ? eidx[E_EDGES + e] : e - E_EDGES;
        atomicAdd(&cnt[d], 1);
    }
}

// ===========================================================================
// scanA: block-local exclusive scan (incl. boundary slot); block total ->
// bsum; zeroes the fill cursor.
// ===========================================================================
__global__ __launch_bounds__(256) void scanA_kernel(
    const int* __restrict__ cnt, int* __restrict__ rowptr, int* __restrict__ bsum,
    int* __restrict__ cursor)
{
    const int i = blockIdx.x * 256 + threadIdx.x;
    const int lane = threadIdx.x & 63;
    const int wave = threadIdx.x >> 6;
    const int v = (i < N_NODES) ? cnt[i] : 0;
    int incl = v;
#pragma unroll
    for (int off = 1; off < 64; off <<= 1) {
        int u = __shfl_up(incl, off);
        if (lane >= off) incl += u;
    }
    __shared__ int ws[4];
    if (lane == 63) ws[wave] = incl;
    __syncthreads();
    int woff = 0;
    if (wave > 0) woff += ws[0];
    if (wave > 1) woff += ws[1];
    if (wave > 2) woff += ws[2];
    if (i <= N_NODES) rowptr[i] = woff + incl - v;   // block-local exclusive
    if (i < N_NODES) cursor[i] = 0;
    if (threadIdx.x == 255) bsum[blockIdx.x] = woff + incl;
}

// Single block: exclusive scan of the 157 block sums in place.
__global__ __launch_bounds__(256) void scanB_kernel(int* __restrict__ bsum)
{
    const int t = threadIdx.x;
    const int lane = t & 63;
    const int wave = t >> 6;
    const int v = (t < SCAN_BLOCKS) ? bsum[t] : 0;
    int incl = v;
#pragma unroll
    for (int off = 1; off < 64; off <<= 1) {
        int u = __shfl_up(incl, off);
        if (lane >= off) incl += u;
    }
    __shared__ int ws[4];
    if (lane == 63) ws[wave] = incl;
    __syncthreads();
    int woff = 0;
    if (wave > 0) woff += ws[0];
    if (wave > 1) woff += ws[1];
    if (wave > 2) woff += ws[2];
    if (t < SCAN_BLOCKS) bsum[t] = woff + incl - v;  // exclusive
}

// Bucket edges by dst (pure bucketing; attention math lives in the gathers).
__global__ __launch_bounds__(256) void fill_kernel(
    const int* __restrict__ eidx, const int* __restrict__ rowptr,
    const int* __restrict__ bsum, int* __restrict__ cursor,
    int* __restrict__ esrc)
{
    const int e = blockIdx.x * 256 + threadIdx.x;
    if (e >= E_TOT) return;
    int s, d;
    if (e < E_EDGES) { s = eidx[e]; d = eidx[E_EDGES + e]; }
    else             { s = d = e - E_EDGES; }
    const int pos = atomicAdd(&cursor[d], 1);
    esrc[rowptr[d] + bsum[d >> 8] + pos] = s;
}

// ===========================================================================
// Gather pass 1: one wave per dst node. Random asrc reads hit the L2-resident
// 640 KB table; bf16 rows; 8-deep pipeline; fused normalize + bias + ELU.
// ===========================================================================
__global__ __launch_bounds__(256) void gather1_kernel(
    const int* __restrict__ rowptr, const int* __restrict__ bsum,
    const int* __restrict__ esrc, const float* __restrict__ asrc,
    const float* __restrict__ adst,
    const ushort* __restrict__ h1b, const float* __restrict__ b,
    float* __restrict__ agg)
{
    const int node = (blockIdx.x * 256 + threadIdx.x) >> 6;
    const int lane = threadIdx.x & 63;
    if (node >= N_NODES) return;
    const int head = lane >> 4;
    const float ad = adst[node * 4 + head];
    const int beg = rowptr[node] + bsum[node >> 8];
    const int end = rowptr[node + 1] + bsum[(node + 1) >> 8];
    float acc0 = 0.f, acc1 = 0.f, den = 0.f;

    int i = beg;
    for (; i + 8 <= end; i += 8) {
        int s[8];
        float a[8];
        uint w[8];
#pragma unroll
        for (int j = 0; j < 8; ++j) s[j] = esrc[i + j];
#pragma unroll
        for (int j = 0; j < 8; ++j) a[j] = asrc[s[j] * 4 + head];
#pragma unroll
        for (int j = 0; j < 8; ++j)
            w[j] = *(const uint*)&h1b[(size_t)s[j] * 128 + lane * 2];
#pragma unroll
        for (int j = 0; j < 8; ++j) {
            float v = a[j] + ad; v = v > 0.f ? v : 0.2f * v;
            const float e = __expf(v);
            den += e;
            acc0 = fmaf(e, bf_lo(w[j]), acc0);
            acc1 = fmaf(e, bf_hi(w[j]), acc1);
        }
    }
    for (; i < end; ++i) {
        const int s = esrc[i];
        float av = asrc[s * 4 + head] + ad;
        av = av > 0.f ? av : 0.2f * av;
        const float ex = __expf(av);
        const uint w = *(const uint*)&h1b[(size_t)s * 128 + lane * 2];
        den += ex;
        acc0 = fmaf(ex, bf_lo(w), acc0);
        acc1 = fmaf(ex, bf_hi(w), acc1);
    }

    const float inv = 1.f / (den + 1e-16f);
    const float2 bv = *(const float2*)&b[lane * 2];
    float o0 = acc0 * inv + bv.x;
    float o1 = acc1 * inv + bv.y;
    o0 = o0 > 0.f ? o0 : expm1f(o0);
    o1 = o1 > 0.f ? o1 : expm1f(o1);
    *(float2*)&agg[(size_t)node * 128 + lane * 2] = make_float2(o0, o1);
}

// ===========================================================================
// GEMM2: h2 = hin @ W2  [40000x128 @ 128x32], fused attention coeffs (1 head)
// ===========================================================================
__global__ __launch_bounds__(256) void gemm2_kernel(
    const float* __restrict__ hin, const float* __restrict__ W,
    const float* __restrict__ a_src, const float* __restrict__ a_dst,
    float* __restrict__ h2, float* __restrict__ asrc, float* __restrict__ adst)
{
    __shared__ float Ws[128 * 32];   // 16 KB
    {
        const float4* Wg = (const float4*)W;
        float4* Wl = (float4*)Ws;
        for (int i = threadIdx.x; i < 128 * 32 / 4; i += 256) Wl[i] = Wg[i];
    }
    __syncthreads();
    const int row0 = blockIdx.x * 64;
    const int tx = threadIdx.x & 7;
    const int ty = threadIdx.x >> 3;

    float acc[2][4];
#pragma unroll
    for (int r = 0; r < 2; ++r)
#pragma unroll
        for (int c = 0; c < 4; ++c) acc[r][c] = 0.f;

    for (int k0 = 0; k0 < 128; k0 += 4) {
        float xv[2][4];
#pragma unroll
        for (int r = 0; r < 2; ++r) {
            float4 t = *(const float4*)&hin[(size_t)(row0 + ty * 2 + r) * 128 + k0];
            xv[r][0] = t.x; xv[r][1] = t.y; xv[r][2] = t.z; xv[r][3] = t.w;
        }
#pragma unroll
        for (int kk = 0; kk < 4; ++kk) {
            float4 w = *(const float4*)&Ws[(k0 + kk) * 32 + tx * 4];
            float wreg[4] = { w.x, w.y, w.z, w.w };
#pragma unroll
            for (int r = 0; r < 2; ++r)
#pragma unroll
                for (int c = 0; c < 4; ++c)
                    acc[r][c] = fmaf(xv[r][kk], wreg[c], acc[r][c]);
        }
    }

    float as[4], ad[4];
#pragma unroll
    for (int c = 0; c < 4; ++c) {
        as[c] = a_src[tx * 4 + c];
        ad[c] = a_dst[tx * 4 + c];
    }
#pragma unroll
    for (int r = 0; r < 2; ++r) {
        const int n = row0 + ty * 2 + r;
        *(float4*)&h2[(size_t)n * 32 + tx * 4] =
            make_float4(acc[r][0], acc[r][1], acc[r][2], acc[r][3]);
        float ps = 0.f, pd = 0.f;
#pragma unroll
        for (int c = 0; c < 4; ++c) {
            ps = fmaf(acc[r][c], as[c], ps);
            pd = fmaf(acc[r][c], ad[c], pd);
        }
        ps += __shfl_xor(ps, 1); ps += __shfl_xor(ps, 2); ps += __shfl_xor(ps, 4);
        pd += __shfl_xor(pd, 1); pd += __shfl_xor(pd, 2); pd += __shfl_xor(pd, 4);
        if ((threadIdx.x & 7) == 0) { asrc[n] = ps; adst[n] = pd; }
    }
}

// ===========================================================================
// Gather pass 2: 32 lanes per dst node, 8-deep pipeline; fused norm+bias+ELU.
// ===========================================================================
__global__ __launch_bounds__(256) void gather2_kernel(
    const int* __restrict__ rowptr, const int* __restrict__ bsum,
    const int* __restrict__ esrc,
    const float* __restrict__ asrc, const float* __restrict__ adst,
    const float* __restrict__ h2, const float* __restrict__ b,
    float* __restrict__ agg)
{
    const int t = blockIdx.x * 256 + threadIdx.x;
    const int node = t >> 5;
    const int c = t & 31;
    if (node >= N_NODES) return;
    const float ad = adst[node];
    const int beg = rowptr[node] + bsum[node >> 8];
    const int end = rowptr[node + 1] + bsum[(node + 1) >> 8];
    float acc = 0.f, den = 0.f;

    int i = beg;
    for (; i + 8 <= end; i += 8) {
        int s[8];
        float a[8], h[8];
#pragma unroll
        for (int j = 0; j < 8; ++j) s[j] = esrc[i + j];
#pragma unroll
        for (int j = 0; j < 8; ++j) a[j] = asrc[s[j]];
#pragma unroll
        for (int j = 0; j < 8; ++j) h[j] = h2[(size_t)s[j] * 32 + c];
#pragma unroll
        for (int j = 0; j < 8; ++j) {
            float v = a[j] + ad; v = v > 0.f ? v : 0.2f * v;
            const float e = __expf(v);
            den += e;
            acc = fmaf(e, h[j], acc);
        }
    }
    for (; i < end; ++i) {
        const int s = esrc[i];
        float av = asrc[s] + ad;
        av = av > 0.f ? av : 0.2f * av;
        const float ex = __expf(av);
        den += ex;
        acc = fmaf(ex, h2[(size_t)s * 32 + c], acc);
    }

    const float inv = 1.f / (den + 1e-16f);
    float o = acc * inv + b[c];
    o = o > 0.f ? o : expm1f(o);
    agg[(size_t)node * 32 + c] = o;
}

// ===========================================================================
// Output GEMM: out = h3 @ W_out + b_out  [40000x32 @ 32x112]
// ===========================================================================
__global__ __launch_bounds__(256) void out_gemm_kernel(
    const float* __restrict__ h3, const float* __restrict__ W,
    const float* __restrict__ b, float* __restrict__ out)
{
    __shared__ float Ws[32 * 112];   // 14 KB
    {
        const float4* Wg = (const float4*)W;
        float4* Wl = (float4*)Ws;
        for (int i = threadIdx.x; i < 32 * 112 / 4; i += 256) Wl[i] = Wg[i];
    }
    __syncthreads();
    const int row0 = blockIdx.x * 32;
    const int tc = threadIdx.x & 15;
    const int tr = threadIdx.x >> 4;

    float acc[2][7];
#pragma unroll
    for (int r = 0; r < 2; ++r)
#pragma unroll
        for (int c = 0; c < 7; ++c) acc[r][c] = 0.f;

    for (int k0 = 0; k0 < 32; k0 += 4) {
        float xv[2][4];
#pragma unroll
        for (int r = 0; r < 2; ++r) {
            float4 t = *(const float4*)&h3[(size_t)(row0 + tr * 2 + r) * 32 + k0];
            xv[r][0] = t.x; xv[r][1] = t.y; xv[r][2] = t.z; xv[r][3] = t.w;
        }
#pragma unroll
        for (int kk = 0; kk < 4; ++kk) {
            float wv[7];
#pragma unroll
            for (int c = 0; c < 7; ++c) wv[c] = Ws[(k0 + kk) * 112 + tc * 7 + c];
#pragma unroll
            for (int r = 0; r < 2; ++r)
#pragma unroll
                for (int c = 0; c < 7; ++c)
                    acc[r][c] = fmaf(xv[r][kk], wv[c], acc[r][c]);
        }
    }
#pragma unroll
    for (int r = 0; r < 2; ++r) {
        const int n = row0 + tr * 2 + r;
#pragma unroll
        for (int c = 0; c < 7; ++c)
            out[(size_t)n * 112 + tc * 7 + c] = acc[r][c] + b[tc * 7 + c];
    }
}

// ===========================================================================
extern "C" void kernel_launch(void* const* d_in, const int* in_sizes, int n_in,
                              void* d_out, int out_size, void* d_ws, size_t ws_size,
                              hipStream_t stream) {
    const float* x      = (const float*)d_in[0];
    const int*   eidx   = (const int*)d_in[1];
    const float* W1     = (const float*)d_in[2];
    const float* a_src1 = (const float*)d_in[3];
    const float* a_dst1 = (const float*)d_in[4];
    const float* b1     = (const float*)d_in[5];
    const float* W2     = (const float*)d_in[6];
    const float* a_src2 = (const float*)d_in[7];
    const float* a_dst2 = (const float*)d_in[8];
    const float* b2     = (const float*)d_in[9];
    const float* W_out  = (const float*)d_in[10];
    const float* b_out  = (const float*)d_in[11];
    float* out = (float*)d_out;

    // ---- workspace layout (~35 MB), all segment sizes multiples of 16 words
    int* rowptr = (int*)d_ws;                // 40064 (uses [0..40000])
    int* cnt    = rowptr + 40064;            // 40064 histogram counts
    int* cursor = cnt + 40064;               // 40064 fill cursor
    int* bsum   = cursor + 40064;            // 192 block sums (exclusive)
    int* esrc   = bsum + 192;                // 680000 CSR edge sources
    ushort* h1b  = (ushort*)(esrc + 680000); // 40000*128 bf16
    float* asrc1 = (float*)(h1b + 5120000);  // 40000*4
    float* adst1 = asrc1 + 160000;           // 40000*4
    float* agg1  = adst1 + 160000;           // 40000*128
    // after gather1, h1b region is dead -> layer-2 buffers overlay it
    float* h2    = (float*)h1b;              // 40000*32
    float* asrc2 = h2 + 1280000;             // 40000
    float* adst2 = asrc2 + 40000;            // 40000
    float* agg2  = adst2 + 40000;            // 40000*32

    // cnt must be zero before gemm1's fused histogram tail
    zero_cnt_kernel<<<(40064 / 4 + 255) / 256, 256, 0, stream>>>((int4*)cnt);

    // Layer-1 GEMM + fused edge histogram
    gemm1_kernel<<<625, 256, 0, stream>>>(x, W1, a_src1, a_dst1, h1b, asrc1, adst1,
                                          eidx, cnt);
    // CSR build (shared by both layers)
    scanA_kernel<<<SCAN_BLOCKS, 256, 0, stream>>>(cnt, rowptr, bsum, cursor);
    scanB_kernel<<<1, 256, 0, stream>>>(bsum);
    fill_kernel<<<(E_TOT + 255) / 256, 256, 0, stream>>>(
        eidx, rowptr, bsum, cursor, esrc);

    // Layer 1 aggregate
    gather1_kernel<<<10000, 256, 0, stream>>>(rowptr, bsum, esrc, asrc1, adst1,
                                              h1b, b1, agg1);

    // Layer 2
    gemm2_kernel<<<625, 256, 0, stream>>>(agg1, W2, a_src2, a_dst2, h2, asrc2, adst2);
    gather2_kernel<<<5000, 256, 0, stream>>>(rowptr, bsum, esrc, asrc2, adst2, h2, b2, agg2);

    // Output projection
    out_gemm_kernel<<<1250, 256, 0, stream>>>(agg2, W_out, b_out, out);
}

// Round 8
// 170.958 us; speedup vs baseline: 1.0380x; 1.0380x over previous
//
#include <hip/hip_runtime.h>

#define N_NODES 40000
#define E_EDGES 640000
#define E_TOT   (E_EDGES + N_NODES)
#define SCAN_BLOCKS ((N_NODES + 255) / 256)   // 157
#define G1_BLOCKS 1250                        // 625 row-tiles x 2 col-panels

typedef unsigned int uint;
typedef unsigned short ushort;

// bf16 helpers (RNE pack, cheap unpack)
__device__ __forceinline__ ushort f2bf(float f) {
    uint u = __float_as_uint(f);
    u += 0x7FFFu + ((u >> 16) & 1u);
    return (ushort)(u >> 16);
}
__device__ __forceinline__ uint pk_bf(float lo, float hi) {
    return (uint)f2bf(lo) | ((uint)f2bf(hi) << 16);
}
__device__ __forceinline__ float bf_lo(uint w) { return __uint_as_float(w << 16); }
__device__ __forceinline__ float bf_hi(uint w) { return __uint_as_float(w & 0xFFFF0000u); }

// ===========================================================================
// Zero histogram counters (tiny; must precede gemm1's fused histogram tail).
// ===========================================================================
__global__ __launch_bounds__(256) void zero_cnt_kernel(int4* __restrict__ cnt4)
{
    const int i = blockIdx.x * 256 + threadIdx.x;
    if (i < 40064 / 4) cnt4[i] = make_int4(0, 0, 0, 0);
}

// ===========================================================================
// GEMM1: h1 = x @ W1  [40000x128 @ 128x128]; h1 stored bf16.
// Tile: 64 rows x 64 cols per block (blockIdx = row_tile*2 + col_panel).
// LDS W panel [128][64] f32 = 32 KB -> 5 blocks/CU; ds_read float4 at
// Ws[k*64 + tx*4]: banks covered 2x -> conflict-free (2-way is free).
// Fused attention coeffs (head-local to each panel) + histogram tail.
// ===========================================================================
__global__ __launch_bounds__(256) void gemm1_kernel(
    const float* __restrict__ x, const float* __restrict__ W,
    const float* __restrict__ a_src, const float* __restrict__ a_dst,
    ushort* __restrict__ h1b, float* __restrict__ asrc, float* __restrict__ adst,
    const int* __restrict__ eidx, int* __restrict__ cnt)
{
    __shared__ float Ws[128 * 64];   // 32 KB
    const int cb = blockIdx.x & 1;        // column panel (cols cb*64 .. +63)
    const int row0 = (blockIdx.x >> 1) * 64;
    {
        const float4* Wg = (const float4*)W;
        float4* Wl = (float4*)Ws;
        for (int i = threadIdx.x; i < 128 * 64 / 4; i += 256) {
            const int r = i >> 4, c = i & 15;       // 16 float4 per LDS row
            Wl[i] = Wg[r * 32 + cb * 16 + c];
        }
    }
    __syncthreads();
    const int tx = threadIdx.x & 15;   // 16 col-groups of 4 cols
    const int ty = threadIdx.x >> 4;   // 16 row-groups of 4 rows

    float acc[4][4];
#pragma unroll
    for (int r = 0; r < 4; ++r)
#pragma unroll
        for (int c = 0; c < 4; ++c) acc[r][c] = 0.f;

    for (int k0 = 0; k0 < 128; k0 += 4) {
        float xv[4][4];
#pragma unroll
        for (int r = 0; r < 4; ++r) {
            float4 t = *(const float4*)&x[(size_t)(row0 + ty * 4 + r) * 128 + k0];
            xv[r][0] = t.x; xv[r][1] = t.y; xv[r][2] = t.z; xv[r][3] = t.w;
        }
#pragma unroll
        for (int kk = 0; kk < 4; ++kk) {
            float4 w = *(const float4*)&Ws[(k0 + kk) * 64 + tx * 4];
            float wreg[4] = { w.x, w.y, w.z, w.w };
#pragma unroll
            for (int r = 0; r < 4; ++r)
#pragma unroll
                for (int c = 0; c < 4; ++c)
                    acc[r][c] = fmaf(xv[r][kk], wreg[c], acc[r][c]);
        }
    }

    // Thread's 4 global cols: cb*64 + tx*4 + c -> head = 2*cb + (tx>>3),
    // within-head offset (tx&7)*4 + c. Reduce over the 8 lanes of (tx&7).
    const int head = 2 * cb + (tx >> 3);
    const int coff = (tx & 7) * 4;
    float as[4], ad[4];
#pragma unroll
    for (int c = 0; c < 4; ++c) {
        as[c] = a_src[head * 32 + coff + c];
        ad[c] = a_dst[head * 32 + coff + c];
    }
#pragma unroll
    for (int r = 0; r < 4; ++r) {
        const int n = row0 + ty * 4 + r;
        uint2 o;
        o.x = pk_bf(acc[r][0], acc[r][1]);
        o.y = pk_bf(acc[r][2], acc[r][3]);
        *(uint2*)&h1b[(size_t)n * 128 + cb * 64 + tx * 4] = o;
        float ps = 0.f, pd = 0.f;
#pragma unroll
        for (int c = 0; c < 4; ++c) {
            ps = fmaf(acc[r][c], as[c], ps);
            pd = fmaf(acc[r][c], ad[c], pd);
        }
        ps += __shfl_xor(ps, 1); ps += __shfl_xor(ps, 2); ps += __shfl_xor(ps, 4);
        pd += __shfl_xor(pd, 1); pd += __shfl_xor(pd, 2); pd += __shfl_xor(pd, 4);
        if ((tx & 7) == 0) {
            asrc[n * 4 + head] = ps;
            adst[n * 4 + head] = pd;
        }
    }

    // ---- fused histogram tail (grid-stride over all edges + self-loops) ----
    for (int e = blockIdx.x * 256 + threadIdx.x; e < E_TOT; e += G1_BLOCKS * 256) {
        const int d = (e < E_EDGES) ? eidx[E_EDGES + e] : e - E_EDGES;
        atomicAdd(&cnt[d], 1);
    }
}

// ===========================================================================
// scanA: block-local exclusive scan (incl. boundary slot); block total ->
// bsum; zeroes the fill cursor.
// ===========================================================================
__global__ __launch_bounds__(256) void scanA_kernel(
    const int* __restrict__ cnt, int* __restrict__ rowptr, int* __restrict__ bsum,
    int* __restrict__ cursor)
{
    const int i = blockIdx.x * 256 + threadIdx.x;
    const int lane = threadIdx.x & 63;
    const int wave = threadIdx.x >> 6;
    const int v = (i < N_NODES) ? cnt[i] : 0;
    int incl = v;
#pragma unroll
    for (int off = 1; off < 64; off <<= 1) {
        int u = __shfl_up(incl, off);
        if (lane >= off) incl += u;
    }
    __shared__ int ws[4];
    if (lane == 63) ws[wave] = incl;
    __syncthreads();
    int woff = 0;
    if (wave > 0) woff += ws[0];
    if (wave > 1) woff += ws[1];
    if (wave > 2) woff += ws[2];
    if (i <= N_NODES) rowptr[i] = woff + incl - v;   // block-local exclusive
    if (i < N_NODES) cursor[i] = 0;
    if (threadIdx.x == 255) bsum[blockIdx.x] = woff + incl;
}

// Single block: exclusive scan of the 157 block sums in place.
__global__ __launch_bounds__(256) void scanB_kernel(int* __restrict__ bsum)
{
    const int t = threadIdx.x;
    const int lane = t & 63;
    const int wave = t >> 6;
    const int v = (t < SCAN_BLOCKS) ? bsum[t] : 0;
    int incl = v;
#pragma unroll
    for (int off = 1; off < 64; off <<= 1) {
        int u = __shfl_up(incl, off);
        if (lane >= off) incl += u;
    }
    __shared__ int ws[4];
    if (lane == 63) ws[wave] = incl;
    __syncthreads();
    int woff = 0;
    if (wave > 0) woff += ws[0];
    if (wave > 1) woff += ws[1];
    if (wave > 2) woff += ws[2];
    if (t < SCAN_BLOCKS) bsum[t] = woff + incl - v;  // exclusive
}

// Bucket edges by dst (pure bucketing; attention math lives in the gathers).
__global__ __launch_bounds__(256) void fill_kernel(
    const int* __restrict__ eidx, const int* __restrict__ rowptr,
    const int* __restrict__ bsum, int* __restrict__ cursor,
    int* __restrict__ esrc)
{
    const int e = blockIdx.x * 256 + threadIdx.x;
    if (e >= E_TOT) return;
    int s, d;
    if (e < E_EDGES) { s = eidx[e]; d = eidx[E_EDGES + e]; }
    else             { s = d = e - E_EDGES; }
    const int pos = atomicAdd(&cursor[d], 1);
    esrc[rowptr[d] + bsum[d >> 8] + pos] = s;
}

// ===========================================================================
// Gather pass 1: one wave per dst node. Random asrc reads hit the L2-resident
// 640 KB table; bf16 rows; 8-deep pipeline; fused normalize + bias + ELU.
// ===========================================================================
__global__ __launch_bounds__(256) void gather1_kernel(
    const int* __restrict__ rowptr, const int* __restrict__ bsum,
    const int* __restrict__ esrc, const float* __restrict__ asrc,
    const float* __restrict__ adst,
    const ushort* __restrict__ h1b, const float* __restrict__ b,
    float* __restrict__ agg)
{
    const int node = (blockIdx.x * 256 + threadIdx.x) >> 6;
    const int lane = threadIdx.x & 63;
    if (node >= N_NODES) return;
    const int head = lane >> 4;
    const float ad = adst[node * 4 + head];
    const int beg = rowptr[node] + bsum[node >> 8];
    const int end = rowptr[node + 1] + bsum[(node + 1) >> 8];
    float acc0 = 0.f, acc1 = 0.f, den = 0.f;

    int i = beg;
    for (; i + 8 <= end; i += 8) {
        int s[8];
        float a[8];
        uint w[8];
#pragma unroll
        for (int j = 0; j < 8; ++j) s[j] = esrc[i + j];
#pragma unroll
        for (int j = 0; j < 8; ++j) a[j] = asrc[s[j] * 4 + head];
#pragma unroll
        for (int j = 0; j < 8; ++j)
            w[j] = *(const uint*)&h1b[(size_t)s[j] * 128 + lane * 2];
#pragma unroll
        for (int j = 0; j < 8; ++j) {
            float v = a[j] + ad; v = v > 0.f ? v : 0.2f * v;
            const float e = __expf(v);
            den += e;
            acc0 = fmaf(e, bf_lo(w[j]), acc0);
            acc1 = fmaf(e, bf_hi(w[j]), acc1);
        }
    }
    for (; i < end; ++i) {
        const int s = esrc[i];
        float av = asrc[s * 4 + head] + ad;
        av = av > 0.f ? av : 0.2f * av;
        const float ex = __expf(av);
        const uint w = *(const uint*)&h1b[(size_t)s * 128 + lane * 2];
        den += ex;
        acc0 = fmaf(ex, bf_lo(w), acc0);
        acc1 = fmaf(ex, bf_hi(w), acc1);
    }

    const float inv = 1.f / (den + 1e-16f);
    const float2 bv = *(const float2*)&b[lane * 2];
    float o0 = acc0 * inv + bv.x;
    float o1 = acc1 * inv + bv.y;
    o0 = o0 > 0.f ? o0 : expm1f(o0);
    o1 = o1 > 0.f ? o1 : expm1f(o1);
    *(float2*)&agg[(size_t)node * 128 + lane * 2] = make_float2(o0, o1);
}

// ===========================================================================
// GEMM2: h2 = hin @ W2  [40000x128 @ 128x32], fused attention coeffs (1 head)
// ===========================================================================
__global__ __launch_bounds__(256) void gemm2_kernel(
    const float* __restrict__ hin, const float* __restrict__ W,
    const float* __restrict__ a_src, const float* __restrict__ a_dst,
    float* __restrict__ h2, float* __restrict__ asrc, float* __restrict__ adst)
{
    __shared__ float Ws[128 * 32];   // 16 KB
    {
        const float4* Wg = (const float4*)W;
        float4* Wl = (float4*)Ws;
        for (int i = threadIdx.x; i < 128 * 32 / 4; i += 256) Wl[i] = Wg[i];
    }
    __syncthreads();
    const int row0 = blockIdx.x * 64;
    const int tx = threadIdx.x & 7;
    const int ty = threadIdx.x >> 3;

    float acc[2][4];
#pragma unroll
    for (int r = 0; r < 2; ++r)
#pragma unroll
        for (int c = 0; c < 4; ++c) acc[r][c] = 0.f;

    for (int k0 = 0; k0 < 128; k0 += 4) {
        float xv[2][4];
#pragma unroll
        for (int r = 0; r < 2; ++r) {
            float4 t = *(const float4*)&hin[(size_t)(row0 + ty * 2 + r) * 128 + k0];
            xv[r][0] = t.x; xv[r][1] = t.y; xv[r][2] = t.z; xv[r][3] = t.w;
        }
#pragma unroll
        for (int kk = 0; kk < 4; ++kk) {
            float4 w = *(const float4*)&Ws[(k0 + kk) * 32 + tx * 4];
            float wreg[4] = { w.x, w.y, w.z, w.w };
#pragma unroll
            for (int r = 0; r < 2; ++r)
#pragma unroll
                for (int c = 0; c < 4; ++c)
                    acc[r][c] = fmaf(xv[r][kk], wreg[c], acc[r][c]);
        }
    }

    float as[4], ad[4];
#pragma unroll
    for (int c = 0; c < 4; ++c) {
        as[c] = a_src[tx * 4 + c];
        ad[c] = a_dst[tx * 4 + c];
    }
#pragma unroll
    for (int r = 0; r < 2; ++r) {
        const int n = row0 + ty * 2 + r;
        *(float4*)&h2[(size_t)n * 32 + tx * 4] =
            make_float4(acc[r][0], acc[r][1], acc[r][2], acc[r][3]);
        float ps = 0.f, pd = 0.f;
#pragma unroll
        for (int c = 0; c < 4; ++c) {
            ps = fmaf(acc[r][c], as[c], ps);
            pd = fmaf(acc[r][c], ad[c], pd);
        }
        ps += __shfl_xor(ps, 1); ps += __shfl_xor(ps, 2); ps += __shfl_xor(ps, 4);
        pd += __shfl_xor(pd, 1); pd += __shfl_xor(pd, 2); pd += __shfl_xor(pd, 4);
        if ((threadIdx.x & 7) == 0) { asrc[n] = ps; adst[n] = pd; }
    }
}

// ===========================================================================
// Gather pass 2: 32 lanes per dst node, 8-deep pipeline; fused norm+bias+ELU.
// ===========================================================================
__global__ __launch_bounds__(256) void gather2_kernel(
    const int* __restrict__ rowptr, const int* __restrict__ bsum,
    const int* __restrict__ esrc,
    const float* __restrict__ asrc, const float* __restrict__ adst,
    const float* __restrict__ h2, const float* __restrict__ b,
    float* __restrict__ agg)
{
    const int t = blockIdx.x * 256 + threadIdx.x;
    const int node = t >> 5;
    const int c = t & 31;
    if (node >= N_NODES) return;
    const float ad = adst[node];
    const int beg = rowptr[node] + bsum[node >> 8];
    const int end = rowptr[node + 1] + bsum[(node + 1) >> 8];
    float acc = 0.f, den = 0.f;

    int i = beg;
    for (; i + 8 <= end; i += 8) {
        int s[8];
        float a[8], h[8];
#pragma unroll
        for (int j = 0; j < 8; ++j) s[j] = esrc[i + j];
#pragma unroll
        for (int j = 0; j < 8; ++j) a[j] = asrc[s[j]];
#pragma unroll
        for (int j = 0; j < 8; ++j) h[j] = h2[(size_t)s[j] * 32 + c];
#pragma unroll
        for (int j = 0; j < 8; ++j) {
            float v = a[j] + ad; v = v > 0.f ? v : 0.2f * v;
            const float e = __expf(v);
            den += e;
            acc = fmaf(e, h[j], acc);
        }
    }
    for (; i < end; ++i) {
        const int s = esrc[i];
        float av = asrc[s] + ad;
        av = av > 0.f ? av : 0.2f * av;
        const float ex = __expf(av);
        den += ex;
        acc = fmaf(ex, h2[(size_t)s * 32 + c], acc);
    }

    const float inv = 1.f / (den + 1e-16f);
    float o = acc * inv + b[c];
    o = o > 0.f ? o : expm1f(o);
    agg[(size_t)node * 32 + c] = o;
}

// ===========================================================================
// Output GEMM: out = h3 @ W_out + b_out  [40000x32 @ 32x112]
// ===========================================================================
__global__ __launch_bounds__(256) void out_gemm_kernel(
    const float* __restrict__ h3, const float* __restrict__ W,
    const float* __restrict__ b, float* __restrict__ out)
{
    __shared__ float Ws[32 * 112];   // 14 KB
    {
        const float4* Wg = (const float4*)W;
        float4* Wl = (float4*)Ws;
        for (int i = threadIdx.x; i < 32 * 112 / 4; i += 256) Wl[i] = Wg[i];
    }
    __syncthreads();
    const int row0 = blockIdx.x * 32;
    const int tc = threadIdx.x & 15;
    const int tr = threadIdx.x >> 4;

    float acc[2][7];
#pragma unroll
    for (int r = 0; r < 2; ++r)
#pragma unroll
        for (int c = 0; c < 7; ++c) acc[r][c] = 0.f;

    for (int k0 = 0; k0 < 32; k0 += 4) {
        float xv[2][4];
#pragma unroll
        for (int r = 0; r < 2; ++r) {
            float4 t = *(const float4*)&h3[(size_t)(row0 + tr * 2 + r) * 32 + k0];
            xv[r][0] = t.x; xv[r][1] = t.y; xv[r][2] = t.z; xv[r][3] = t.w;
        }
#pragma unroll
        for (int kk = 0; kk < 4; ++kk) {
            float wv[7];
#pragma unroll
            for (int c = 0; c < 7; ++c) wv[c] = Ws[(k0 + kk) * 112 + tc * 7 + c];
#pragma unroll
            for (int r = 0; r < 2; ++r)
#pragma unroll
                for (int c = 0; c < 7; ++c)
                    acc[r][c] = fmaf(xv[r][kk], wv[c], acc[r][c]);
        }
    }
#pragma unroll
    for (int r = 0; r < 2; ++r) {
        const int n = row0 + tr * 2 + r;
#pragma unroll
        for (int c = 0; c < 7; ++c)
            out[(size_t)n * 112 + tc * 7 + c] = acc[r][c] + b[tc * 7 + c];
    }
}

// ===========================================================================
extern "C" void kernel_launch(void* const* d_in, const int* in_sizes, int n_in,
                              void* d_out, int out_size, void* d_ws, size_t ws_size,
                              hipStream_t stream) {
    const float* x      = (const float*)d_in[0];
    const int*   eidx   = (const int*)d_in[1];
    const float* W1     = (const float*)d_in[2];
    const float* a_src1 = (const float*)d_in[3];
    const float* a_dst1 = (const float*)d_in[4];
    const float* b1     = (const float*)d_in[5];
    const float* W2     = (const float*)d_in[6];
    const float* a_src2 = (const float*)d_in[7];
    const float* a_dst2 = (const float*)d_in[8];
    const float* b2     = (const float*)d_in[9];
    const float* W_out  = (const float*)d_in[10];
    const float* b_out  = (const float*)d_in[11];
    float* out = (float*)d_out;

    // ---- workspace layout (~35 MB), all segment sizes multiples of 16 words
    int* rowptr = (int*)d_ws;                // 40064 (uses [0..40000])
    int* cnt    = rowptr + 40064;            // 40064 histogram counts
    int* cursor = cnt + 40064;               // 40064 fill cursor
    int* bsum   = cursor + 40064;            // 192 block sums (exclusive)
    int* esrc   = bsum + 192;                // 680000 CSR edge sources
    ushort* h1b  = (ushort*)(esrc + 680000); // 40000*128 bf16
    float* asrc1 = (float*)(h1b + 5120000);  // 40000*4
    float* adst1 = asrc1 + 160000;           // 40000*4
    float* agg1  = adst1 + 160000;           // 40000*128
    // after gather1, h1b region is dead -> layer-2 buffers overlay it
    float* h2    = (float*)h1b;              // 40000*32
    float* asrc2 = h2 + 1280000;             // 40000
    float* adst2 = asrc2 + 40000;            // 40000
    float* agg2  = adst2 + 40000;            // 40000*32

    // cnt must be zero before gemm1's fused histogram tail
    zero_cnt_kernel<<<(40064 / 4 + 255) / 256, 256, 0, stream>>>((int4*)cnt);

    // Layer-1 GEMM + fused edge histogram
    gemm1_kernel<<<G1_BLOCKS, 256, 0, stream>>>(x, W1, a_src1, a_dst1, h1b,
                                                asrc1, adst1, eidx, cnt);
    // CSR build (shared by both layers)
    scanA_kernel<<<SCAN_BLOCKS, 256, 0, stream>>>(cnt, rowptr, bsum, cursor);
    scanB_kernel<<<1, 256, 0, stream>>>(bsum);
    fill_kernel<<<(E_TOT + 255) / 256, 256, 0, stream>>>(
        eidx, rowptr, bsum, cursor, esrc);

    // Layer 1 aggregate
    gather1_kernel<<<10000, 256, 0, stream>>>(rowptr, bsum, esrc, asrc1, adst1,
                                              h1b, b1, agg1);

    // Layer 2
    gemm2_kernel<<<625, 256, 0, stream>>>(agg1, W2, a_src2, a_dst2, h2, asrc2, adst2);
    gather2_kernel<<<5000, 256, 0, stream>>>(rowptr, bsum, esrc, asrc2, adst2, h2, b2, agg2);

    // Output projection
    out_gemm_kernel<<<1250, 256, 0, stream>>>(agg2, W_out, b_out, out);
}